// Round 2
// baseline (390.993 us; speedup 1.0000x reference)
//
#include <hip/hip_runtime.h>

#define NNODES 100000
#define NEDGES 1600000
#define IND 128
#define HIDD 128
#define OUTD 64

// bucketed CSR build
#define BSHIFT 9
#define BSIZE  512
#define NBUCK  ((NNODES + BSIZE - 1) / BSIZE)        // 196
#define SLACK  9216                                  // per-bucket staging stride (mean 8192 + 11 sigma)
#define BIN_EPB  8192
#define SEG_CAP  10240

#define HALFN 50000

typedef unsigned int  uint32;
typedef __attribute__((ext_vector_type(8))) short short8;
typedef __attribute__((ext_vector_type(4))) float floatx4;
typedef __attribute__((ext_vector_type(4))) unsigned int uivec4;
typedef __attribute__((ext_vector_type(4))) float fvec4;

// ---------- bf16 helpers ----------
__device__ __forceinline__ unsigned short f2bf(float f) {
    union { float f; uint32 u; } x; x.f = f;
    uint32 u = x.u;
    return (unsigned short)((u + 0x7fffu + ((u >> 16) & 1u)) >> 16);   // RNE
}
__device__ __forceinline__ float bflo(uint32 u) {
    union { uint32 i; float f; } x; x.i = u << 16; return x.f;
}
__device__ __forceinline__ float bfhi(uint32 u) {
    union { uint32 i; float f; } x; x.i = u & 0xffff0000u; return x.f;
}

// ---------- phase A: bin (src,dst) into fixed-slack bucket staging ----------
__global__ void k_bin(const int* __restrict__ src, const int* __restrict__ dst,
                      int* __restrict__ bcnt, uint32* __restrict__ staging, int e) {
    __shared__ int lh[NBUCK];
    __shared__ int lcur[NBUCK];
    const int tid = threadIdx.x;
    for (int i = tid; i < NBUCK; i += 256) lh[i] = 0;
    __syncthreads();

    int start = blockIdx.x * BIN_EPB;
    int end = min(start + BIN_EPB, e);

    for (int i = start + tid; i < end; i += 256)
        atomicAdd(&lh[dst[i] >> BSHIFT], 1);
    __syncthreads();

    for (int i = tid; i < NBUCK; i += 256)
        lcur[i] = lh[i] ? atomicAdd(&bcnt[i], lh[i]) : 0;
    __syncthreads();

    for (int i = start + tid; i < end; i += 256) {
        int d = dst[i], s = src[i];
        int b = d >> BSHIFT;
        int pos = atomicAdd(&lcur[b], 1);
        if (pos < SLACK)
            staging[b * SLACK + pos] = ((uint32)(d & (BSIZE - 1)) << 17) | (uint32)s;
    }
}

// ---------- phase B: scan bucket counts (1 block) -> boff ----------
__global__ void k_bscan(const int* __restrict__ bcnt, int* __restrict__ boff) {
    __shared__ int buf[256];
    const int tid = threadIdx.x;
    int v = (tid < NBUCK) ? bcnt[tid] : 0;
    buf[tid] = v;
    __syncthreads();
    for (int off = 1; off < 256; off <<= 1) {
        int t = (tid >= off) ? buf[tid - off] : 0;
        __syncthreads();
        buf[tid] += t;
        __syncthreads();
    }
    if (tid < NBUCK) boff[tid] = buf[tid] - v;
    if (tid == 255) boff[NBUCK] = buf[255];
}

// ---------- phase C (fused): per-bucket counts + dinv + row_ptr + counting-sort csr ----------
__global__ void k_fill3(const uint32* __restrict__ staging, const int* __restrict__ bcnt,
                        const int* __restrict__ boff,
                        int* __restrict__ row_ptr, int* __restrict__ csr_src,
                        float* __restrict__ dinv, int n) {
    __shared__ int nc[BSIZE];
    __shared__ int lcur[BSIZE];
    __shared__ int sbuf[256];
    __shared__ int seg[SEG_CAP];    // 40 KB
    const int b = blockIdx.x;
    const int base = b << BSHIFT;
    const int tid = threadIdx.x;
    const int nn = min(BSIZE, n - base);

    for (int i = tid; i < BSIZE; i += 256) nc[i] = 0;
    __syncthreads();

    const uint32* st = staging + (size_t)b * SLACK;
    const int cnt = bcnt[b];
    for (int i = tid; i < cnt; i += 256)
        atomicAdd(&nc[st[i] >> 17], 1);
    __syncthreads();

    int a0 = nc[2 * tid], a1 = nc[2 * tid + 1];
    sbuf[tid] = a0 + a1;
    __syncthreads();
    for (int off = 1; off < 256; off <<= 1) {
        int t = (tid >= off) ? sbuf[tid - off] : 0;
        __syncthreads();
        sbuf[tid] += t;
        __syncthreads();
    }
    int ex = sbuf[tid] - (a0 + a1);
    const int r0 = boff[b];
    if (2 * tid < nn) {
        row_ptr[base + 2 * tid] = r0 + ex;
        dinv[base + 2 * tid] = rsqrtf((float)(a0 + 1));
    }
    if (2 * tid + 1 < nn) {
        row_ptr[base + 2 * tid + 1] = r0 + ex + a0;
        dinv[base + 2 * tid + 1] = rsqrtf((float)(a1 + 1));
    }
    lcur[2 * tid] = ex;
    lcur[2 * tid + 1] = ex + a0;
    if (b == (int)gridDim.x - 1 && tid == 255) row_ptr[n] = boff[NBUCK];
    __syncthreads();

    for (int i = tid; i < cnt; i += 256) {
        uint32 p = st[i];
        int dl = (int)(p >> 17);
        int s  = (int)(p & 0x1FFFFu);
        int pos = atomicAdd(&lcur[dl], 1);
        if (pos < SEG_CAP) seg[pos] = s;
        else               csr_src[r0 + pos] = s;
    }
    __syncthreads();
    int lim = min(cnt, SEG_CAP);
    for (int i = tid; i < lim; i += 256) csr_src[r0 + i] = seg[i];
}

// ---------- both weight transposes in one launch ----------
__global__ void k_wt_both(const float* __restrict__ W1, const float* __restrict__ W2,
                          unsigned short* __restrict__ wt1, unsigned short* __restrict__ wt2) {
    int idx = blockIdx.x * 256 + threadIdx.x;
    if (idx < IND * HIDD) {
        int k = idx / HIDD, m = idx - k * HIDD;
        wt1[m * IND + k] = f2bf(W1[idx]);
    } else {
        int j = idx - IND * HIDD;
        if (j < HIDD * OUTD) {
            int k = j / OUTD, m = j - k * OUTD;
            wt2[m * HIDD + k] = f2bf(W2[j]);
        }
    }
}

// ---------- MFMA bf16 GEMM: C chunked [M/16][n][16] (bf16, premult dinv) = A[n x K] @ W ----------
// ABF16=true reads A in chunked bf16 layout [K/16][n][16]; false reads f32 node-major [n][K].
template<int K, int M, bool ABF16>
__launch_bounds__(256)
__global__ void gemm_mfma(const void* __restrict__ Ap, const unsigned short* __restrict__ WT,
                          const float* __restrict__ dinv, unsigned short* __restrict__ C, int n) {
    constexpr int KP = K + 8;
    constexpr int NT = M / 16;
    __shared__ unsigned short Asl[64 * KP];
    __shared__ unsigned short Wsl[M * KP];

    const int tid = threadIdx.x;
    const int row0 = blockIdx.x * 64;

    {
        constexpr int SEG = (K * 2) / 16;
        const uint4* srcp = (const uint4*)WT;
        for (int idx = tid; idx < M * SEG; idx += 256) {
            int r = idx / SEG, s = idx - r * SEG;
            *(uint4*)(Wsl + r * KP + s * 8) = srcp[idx];
        }
    }
    if constexpr (ABF16) {
        constexpr int U4R = K / 8;                    // 16B segs per row
        const unsigned short* Ab = (const unsigned short*)Ap;
        for (int idx = tid; idx < 64 * U4R; idx += 256) {
            int r = idx / U4R, s = idx - r * U4R;     // seg s = features [s*8, s*8+8)
            int grow = row0 + r; if (grow >= n) grow = n - 1;
            // chunked source: chunk = s>>1, half = s&1
            *(uint4*)(Asl + r * KP + s * 8) =
                *(const uint4*)(Ab + ((size_t)(s >> 1) * n + grow) * 16 + (s & 1) * 8);
        }
    } else {
        constexpr int F4R = K / 4;
        const float* Af = (const float*)Ap;
        for (int idx = tid; idx < 64 * F4R; idx += 256) {
            int r = idx / F4R, s = idx - r * F4R;
            int grow = row0 + r; if (grow >= n) grow = n - 1;
            float4 v = *(const float4*)(Af + (size_t)grow * K + s * 4);
            uint32 p0 = (uint32)f2bf(v.x) | ((uint32)f2bf(v.y) << 16);
            uint32 p1 = (uint32)f2bf(v.z) | ((uint32)f2bf(v.w) << 16);
            *(uint2*)(Asl + r * KP + s * 4) = make_uint2(p0, p1);
        }
    }
    __syncthreads();

    const int lane = tid & 63;
    const int wave = tid >> 6;
    const int mm = lane & 15;
    const int qq = lane >> 4;

    floatx4 acc[NT];
#pragma unroll
    for (int t = 0; t < NT; t++) acc[t] = (floatx4){0.f, 0.f, 0.f, 0.f};

#pragma unroll
    for (int kc = 0; kc < K / 32; kc++) {
        short8 a = *(const short8*)(Asl + (wave * 16 + mm) * KP + kc * 32 + qq * 8);
#pragma unroll
        for (int t = 0; t < NT; t++) {
            short8 b = *(const short8*)(Wsl + (t * 16 + mm) * KP + kc * 32 + qq * 8);
            acc[t] = __builtin_amdgcn_mfma_f32_16x16x32_bf16(a, b, acc[t], 0, 0, 0);
        }
    }

    // chunked C write: feature f = t*16+mm -> chunk t, slot mm
#pragma unroll
    for (int r = 0; r < 4; r++) {
        int grow = row0 + wave * 16 + qq * 4 + r;
        if (grow < n) {
            float dvv = dinv[grow];
#pragma unroll
            for (int t = 0; t < NT; t++)
                C[((size_t)t * n + grow) * 16 + mm] = f2bf(acc[t][r] * dvv);
        }
    }
}

// ---------- feature-chunked, XCD-pinned gather-aggregate ----------
// h is chunk-major [CH_total][n][16] bf16, premultiplied by dinv of source.
// CH==8: chunk = bid&7 (one chunk per XCD), all n nodes per chunk.
// CH==4: chunk = (bid&7)&3, XCD pair splits node range in half.
// Per edge each lane-pair reads 32B from a 3.2MB chunk table that stays
// resident in the XCD's private 4MB L2 -> random reads become L2 hits.
template<int CH, bool RELU, bool OBF16>
__launch_bounds__(256)
__global__ void gather_c(const unsigned short* __restrict__ h,
                         const int* __restrict__ row_ptr,
                         const int* __restrict__ csr_src,
                         const float* __restrict__ dinv,
                         const float* __restrict__ bias,
                         void* __restrict__ outp, int n) {
    const int bid = blockIdx.x;
    const int xcd = bid & 7;
    int chunk, v0, vend;
    if constexpr (CH == 8) {
        chunk = xcd;
        v0 = (bid >> 3) * 128;
        vend = n;
    } else {                       // CH == 4
        chunk = xcd & 3;
        const int sub = xcd >> 2;
        v0 = sub * HALFN + (bid >> 3) * 128;
        vend = min(n, sub * HALFN + HALFN);
    }
    const int g  = threadIdx.x >> 1;       // node within block: 0..127
    const int l8 = (threadIdx.x & 1) * 8;  // feature sub-slot within chunk
    const int v = v0 + g;
    if (v >= vend) return;

    const unsigned short* __restrict__ hc = h + (size_t)chunk * n * 16;
    const float dv = dinv[v];

    float acc[8];
    {   // self-loop term (table row already premultiplied by dinv[v])
        uint4 u = *(const uint4*)(hc + (size_t)v * 16 + l8);
        acc[0] = bflo(u.x); acc[1] = bfhi(u.x);
        acc[2] = bflo(u.y); acc[3] = bfhi(u.y);
        acc[4] = bflo(u.z); acc[5] = bfhi(u.z);
        acc[6] = bflo(u.w); acc[7] = bfhi(u.w);
    }

    int j   = row_ptr[v];
    const int end = row_ptr[v + 1];
    for (; j + 3 < end; j += 4) {
        int s0 = __builtin_nontemporal_load(csr_src + j);
        int s1 = __builtin_nontemporal_load(csr_src + j + 1);
        int s2 = __builtin_nontemporal_load(csr_src + j + 2);
        int s3 = __builtin_nontemporal_load(csr_src + j + 3);
        uint4 u0 = *(const uint4*)(hc + (size_t)s0 * 16 + l8);
        uint4 u1 = *(const uint4*)(hc + (size_t)s1 * 16 + l8);
        uint4 u2 = *(const uint4*)(hc + (size_t)s2 * 16 + l8);
        uint4 u3 = *(const uint4*)(hc + (size_t)s3 * 16 + l8);
        acc[0] += (bflo(u0.x) + bflo(u1.x)) + (bflo(u2.x) + bflo(u3.x));
        acc[1] += (bfhi(u0.x) + bfhi(u1.x)) + (bfhi(u2.x) + bfhi(u3.x));
        acc[2] += (bflo(u0.y) + bflo(u1.y)) + (bflo(u2.y) + bflo(u3.y));
        acc[3] += (bfhi(u0.y) + bfhi(u1.y)) + (bfhi(u2.y) + bfhi(u3.y));
        acc[4] += (bflo(u0.z) + bflo(u1.z)) + (bflo(u2.z) + bflo(u3.z));
        acc[5] += (bfhi(u0.z) + bfhi(u1.z)) + (bfhi(u2.z) + bfhi(u3.z));
        acc[6] += (bflo(u0.w) + bflo(u1.w)) + (bflo(u2.w) + bflo(u3.w));
        acc[7] += (bfhi(u0.w) + bfhi(u1.w)) + (bfhi(u2.w) + bfhi(u3.w));
    }
    for (; j < end; j++) {
        int s0 = __builtin_nontemporal_load(csr_src + j);
        uint4 u0 = *(const uint4*)(hc + (size_t)s0 * 16 + l8);
        acc[0] += bflo(u0.x); acc[1] += bfhi(u0.x);
        acc[2] += bflo(u0.y); acc[3] += bfhi(u0.y);
        acc[4] += bflo(u0.z); acc[5] += bfhi(u0.z);
        acc[6] += bflo(u0.w); acc[7] += bfhi(u0.w);
    }

#pragma unroll
    for (int i = 0; i < 8; i++) {
        acc[i] = acc[i] * dv + bias[chunk * 16 + l8 + i];
        if (RELU) acc[i] = fmaxf(acc[i], 0.0f);
    }

    if constexpr (OBF16) {
        // chunked bf16 output [CH][n][16] — fully coalesced 32B/node
        uivec4 p;
#pragma unroll
        for (int c = 0; c < 4; c++)
            p[c] = (uint32)f2bf(acc[2 * c]) | ((uint32)f2bf(acc[2 * c + 1]) << 16);
        __builtin_nontemporal_store(p,
            (uivec4*)((unsigned short*)outp + ((size_t)chunk * n + v) * 16 + l8));
    } else {
        // node-major f32 output [n][OUTD]
        float* op = (float*)outp + (size_t)v * OUTD + chunk * 16 + l8;
        fvec4 a0 = {acc[0], acc[1], acc[2], acc[3]};
        fvec4 a1 = {acc[4], acc[5], acc[6], acc[7]};
        __builtin_nontemporal_store(a0, (fvec4*)op);
        __builtin_nontemporal_store(a1, (fvec4*)(op + 4));
    }
}

extern "C" void kernel_launch(void* const* d_in, const int* in_sizes, int n_in,
                              void* d_out, int out_size, void* d_ws, size_t ws_size,
                              hipStream_t stream) {
    const float* x  = (const float*)d_in[0];
    const float* W1 = (const float*)d_in[1];
    const float* b1 = (const float*)d_in[2];
    const float* W2 = (const float*)d_in[3];
    const float* b2 = (const float*)d_in[4];
    const int*   ei = (const int*)d_in[5];
    const int* src = ei;            // edge_index[0]
    const int* dst = ei + NEDGES;   // edge_index[1]
    float* out = (float*)d_out;

    // workspace layout (16B-aligned chunks):
    char* ws = (char*)d_ws;
    float*  dinv    = (float*)ws;   ws += (size_t)NNODES * 4;
    int*    row_ptr = (int*)ws;     ws += (size_t)(NNODES + 4) * 4;
    int*    bcnt    = (int*)ws;     ws += 256 * 4;
    int*    boff    = (int*)ws;     ws += 260 * 4;
    unsigned short* wt1 = (unsigned short*)ws;  ws += (size_t)IND * HIDD * 2;
    unsigned short* wt2 = (unsigned short*)ws;  ws += (size_t)HIDD * OUTD * 2;
    int*    csr_src = (int*)ws;     ws += (size_t)NEDGES * 4;
    uint32* staging = (uint32*)ws;  ws += (size_t)NBUCK * SLACK * 4;   // 7.2 MB
    unsigned short* hr  = (unsigned short*)ws;  ws += (size_t)NNODES * HIDD * 2;  // chunked bf16 relu output
    unsigned short* hbf = (unsigned short*)ws;                                     // chunked bf16 table

    // ---- CSR build (3 kernels, no global histogram pass) ----
    hipMemsetAsync(bcnt, 0, 256 * 4, stream);
    k_bin<<<(NEDGES + BIN_EPB - 1) / BIN_EPB, 256, 0, stream>>>(src, dst, bcnt, staging, NEDGES);
    k_bscan<<<1, 256, 0, stream>>>(bcnt, boff);
    k_fill3<<<NBUCK, 256, 0, stream>>>(staging, bcnt, boff, row_ptr, csr_src, dinv, NNODES);

    // ---- weight transposes (bf16) ----
    k_wt_both<<<(IND * HIDD + HIDD * OUTD + 255) / 256, 256, 0, stream>>>(W1, W2, wt1, wt2);

    const int NB1 = (NNODES + 127) / 128;   // node-blocks per chunk (layer 1)
    const int NB2 = (HALFN  + 127) / 128;   // node-blocks per half-range (layer 2)

    // ---- layer 1: hbf(chunked bf16) = (x @ W1)*dinv ; hr(chunked bf16) = relu(gather*dv + b1) ----
    gemm_mfma<IND, HIDD, false><<<(NNODES + 63) / 64, 256, 0, stream>>>(
        x, wt1, dinv, hbf, NNODES);
    gather_c<8, true, true><<<8 * NB1, 256, 0, stream>>>(
        hbf, row_ptr, csr_src, dinv, b1, hr, NNODES);

    // ---- layer 2: hbf(chunked bf16) = (hr @ W2)*dinv ; out(f32) = gather*dv + b2 ----
    gemm_mfma<HIDD, OUTD, true><<<(NNODES + 63) / 64, 256, 0, stream>>>(
        hr, wt2, dinv, hbf, NNODES);
    gather_c<4, false, false><<<8 * NB2, 256, 0, stream>>>(
        hbf, row_ptr, csr_src, dinv, b2, out, NNODES);
}

// Round 3
// 326.713 us; speedup vs baseline: 1.1967x; 1.1967x over previous
//
#include <hip/hip_runtime.h>

#define NNODES 100000
#define NEDGES 1600000
#define IND 128
#define HIDD 128
#define OUTD 64

// bucketed CSR build
#define BSHIFT 9
#define BSIZE  512
#define NBUCK  ((NNODES + BSIZE - 1) / BSIZE)        // 196
#define SLACK  9216                                  // per-bucket staging stride (mean 8192 + 11 sigma)
#define BIN_EPB  8192
#define SEG_CAP  10240
#define BINB   ((NEDGES + BIN_EPB - 1) / BIN_EPB)    // 196
#define WTB    ((IND * HIDD + HIDD * OUTD + 255) / 256)  // 96

typedef unsigned int  uint32;
typedef __attribute__((ext_vector_type(8))) short short8;
typedef __attribute__((ext_vector_type(4))) float floatx4;
typedef __attribute__((ext_vector_type(4))) unsigned int uivec4;
typedef __attribute__((ext_vector_type(4))) float fvec4;

// ---------- bf16 helpers ----------
__device__ __forceinline__ unsigned short f2bf(float f) {
    union { float f; uint32 u; } x; x.f = f;
    uint32 u = x.u;
    return (unsigned short)((u + 0x7fffu + ((u >> 16) & 1u)) >> 16);   // RNE
}
__device__ __forceinline__ float bflo(uint32 u) {
    union { uint32 i; float f; } x; x.i = u << 16; return x.f;
}
__device__ __forceinline__ float bfhi(uint32 u) {
    union { uint32 i; float f; } x; x.i = u & 0xffff0000u; return x.f;
}

// ---------- phase A: bin (src,dst) into bucket staging; tail blocks do weight transposes ----------
__global__ void k_bin(const int* __restrict__ src, const int* __restrict__ dst,
                      int* __restrict__ bcnt, uint32* __restrict__ staging, int e,
                      const float* __restrict__ W1, const float* __restrict__ W2,
                      unsigned short* __restrict__ wt1, unsigned short* __restrict__ wt2) {
    const int tid = threadIdx.x;
    if (blockIdx.x >= BINB) {
        // weight transpose blocks
        int idx = (blockIdx.x - BINB) * 256 + tid;
        if (idx < IND * HIDD) {
            int k = idx / HIDD, m = idx - k * HIDD;
            wt1[m * IND + k] = f2bf(W1[idx]);
        } else {
            int j = idx - IND * HIDD;
            if (j < HIDD * OUTD) {
                int k = j / OUTD, m = j - k * OUTD;
                wt2[m * HIDD + k] = f2bf(W2[j]);
            }
        }
        return;
    }

    __shared__ int lh[NBUCK];
    __shared__ int lcur[NBUCK];
    for (int i = tid; i < NBUCK; i += 256) lh[i] = 0;
    __syncthreads();

    int start = blockIdx.x * BIN_EPB;
    int end = min(start + BIN_EPB, e);

    for (int i = start + tid; i < end; i += 256)
        atomicAdd(&lh[dst[i] >> BSHIFT], 1);
    __syncthreads();

    for (int i = tid; i < NBUCK; i += 256)
        lcur[i] = lh[i] ? atomicAdd(&bcnt[i], lh[i]) : 0;
    __syncthreads();

    for (int i = start + tid; i < end; i += 256) {
        int d = dst[i], s = src[i];
        int b = d >> BSHIFT;
        int pos = atomicAdd(&lcur[b], 1);
        if (pos < SLACK)
            staging[b * SLACK + pos] = ((uint32)(d & (BSIZE - 1)) << 17) | (uint32)s;
    }
}

// ---------- phase C (fused): self-scan of bcnt + per-bucket counts + dinv + row_ptr + counting-sort csr ----------
__global__ void k_fill3(const uint32* __restrict__ staging, const int* __restrict__ bcnt,
                        int* __restrict__ row_ptr, int* __restrict__ csr_src,
                        float* __restrict__ dinv, int n) {
    __shared__ int nc[BSIZE];
    __shared__ int lcur[BSIZE];
    __shared__ int sbuf[256];
    __shared__ int boffl[NBUCK + 1];
    __shared__ int seg[SEG_CAP];    // 40 KB
    const int b = blockIdx.x;
    const int base = b << BSHIFT;
    const int tid = threadIdx.x;
    const int nn = min(BSIZE, n - base);

    for (int i = tid; i < BSIZE; i += 256) nc[i] = 0;

    // self-scan of bucket counts -> exclusive offsets (replaces k_bscan kernel)
    int vb = (tid < NBUCK) ? bcnt[tid] : 0;
    sbuf[tid] = vb;
    __syncthreads();
    for (int off = 1; off < 256; off <<= 1) {
        int t = (tid >= off) ? sbuf[tid - off] : 0;
        __syncthreads();
        sbuf[tid] += t;
        __syncthreads();
    }
    if (tid < NBUCK) boffl[tid] = sbuf[tid] - vb;
    if (tid == 255) boffl[NBUCK] = sbuf[255];
    __syncthreads();

    const uint32* st = staging + (size_t)b * SLACK;
    const int cnt = bcnt[b];
    for (int i = tid; i < cnt; i += 256)
        atomicAdd(&nc[st[i] >> 17], 1);
    __syncthreads();

    int a0 = nc[2 * tid], a1 = nc[2 * tid + 1];
    sbuf[tid] = a0 + a1;
    __syncthreads();
    for (int off = 1; off < 256; off <<= 1) {
        int t = (tid >= off) ? sbuf[tid - off] : 0;
        __syncthreads();
        sbuf[tid] += t;
        __syncthreads();
    }
    int ex = sbuf[tid] - (a0 + a1);
    const int r0 = boffl[b];
    if (2 * tid < nn) {
        row_ptr[base + 2 * tid] = r0 + ex;
        dinv[base + 2 * tid] = rsqrtf((float)(a0 + 1));
    }
    if (2 * tid + 1 < nn) {
        row_ptr[base + 2 * tid + 1] = r0 + ex + a0;
        dinv[base + 2 * tid + 1] = rsqrtf((float)(a1 + 1));
    }
    lcur[2 * tid] = ex;
    lcur[2 * tid + 1] = ex + a0;
    if (b == (int)gridDim.x - 1 && tid == 255) row_ptr[n] = boffl[NBUCK];
    __syncthreads();

    for (int i = tid; i < cnt; i += 256) {
        uint32 p = st[i];
        int dl = (int)(p >> 17);
        int s  = (int)(p & 0x1FFFFu);
        int pos = atomicAdd(&lcur[dl], 1);
        if (pos < SEG_CAP) seg[pos] = s;
        else               csr_src[r0 + pos] = s;
    }
    __syncthreads();
    int lim = min(cnt, SEG_CAP);
    for (int i = tid; i < lim; i += 256) csr_src[r0 + i] = seg[i];
}

// ---------- MFMA bf16 GEMM: C[n x M](bf16, premult dinv) = A[n x K] @ W ----------
template<int K, int M, bool ABF16>
__launch_bounds__(256)
__global__ void gemm_mfma(const void* __restrict__ Ap, const unsigned short* __restrict__ WT,
                          const float* __restrict__ dinv, unsigned short* __restrict__ C, int n) {
    constexpr int KP = K + 8;
    constexpr int NT = M / 16;
    __shared__ unsigned short Asl[64 * KP];
    __shared__ unsigned short Wsl[M * KP];

    const int tid = threadIdx.x;
    const int row0 = blockIdx.x * 64;

    {
        constexpr int SEG = (K * 2) / 16;
        const uint4* srcp = (const uint4*)WT;
        for (int idx = tid; idx < M * SEG; idx += 256) {
            int r = idx / SEG, s = idx - r * SEG;
            *(uint4*)(Wsl + r * KP + s * 8) = srcp[idx];
        }
    }
    if constexpr (ABF16) {
        constexpr int U4R = K / 8;
        const unsigned short* Ab = (const unsigned short*)Ap;
        for (int idx = tid; idx < 64 * U4R; idx += 256) {
            int r = idx / U4R, s = idx - r * U4R;
            int grow = row0 + r; if (grow >= n) grow = n - 1;
            *(uint4*)(Asl + r * KP + s * 8) = *(const uint4*)(Ab + (size_t)grow * K + s * 8);
        }
    } else {
        constexpr int F4R = K / 4;
        const float* Af = (const float*)Ap;
        for (int idx = tid; idx < 64 * F4R; idx += 256) {
            int r = idx / F4R, s = idx - r * F4R;
            int grow = row0 + r; if (grow >= n) grow = n - 1;
            float4 v = *(const float4*)(Af + (size_t)grow * K + s * 4);
            uint32 p0 = (uint32)f2bf(v.x) | ((uint32)f2bf(v.y) << 16);
            uint32 p1 = (uint32)f2bf(v.z) | ((uint32)f2bf(v.w) << 16);
            *(uint2*)(Asl + r * KP + s * 4) = make_uint2(p0, p1);
        }
    }
    __syncthreads();

    const int lane = tid & 63;
    const int wave = tid >> 6;
    const int mm = lane & 15;
    const int qq = lane >> 4;

    floatx4 acc[NT];
#pragma unroll
    for (int t = 0; t < NT; t++) acc[t] = (floatx4){0.f, 0.f, 0.f, 0.f};

#pragma unroll
    for (int kc = 0; kc < K / 32; kc++) {
        short8 a = *(const short8*)(Asl + (wave * 16 + mm) * KP + kc * 32 + qq * 8);
#pragma unroll
        for (int t = 0; t < NT; t++) {
            short8 b = *(const short8*)(Wsl + (t * 16 + mm) * KP + kc * 32 + qq * 8);
            acc[t] = __builtin_amdgcn_mfma_f32_16x16x32_bf16(a, b, acc[t], 0, 0, 0);
        }
    }

#pragma unroll
    for (int r = 0; r < 4; r++) {
        int grow = row0 + wave * 16 + qq * 4 + r;
        if (grow < n) {
            float dv = dinv[grow];
#pragma unroll
            for (int t = 0; t < NT; t++)
                C[(size_t)grow * M + t * 16 + mm] = f2bf(acc[t][r] * dv);
        }
    }
}

// ---------- gather-aggregate over premultiplied bf16 table (node-major rows) ----------
// NT hints on the index stream and output stores keep L2/LLC capacity for the h-table,
// which is the only structure with reuse.
template<int M, bool RELU, bool OBF16>
__launch_bounds__(256)
__global__ void gather_k(const unsigned short* __restrict__ h,
                         const int* __restrict__ row_ptr,
                         const int* __restrict__ csr_src,
                         const float* __restrict__ dinv,
                         const float* __restrict__ bias,
                         void* __restrict__ outp, int n) {
    constexpr int LPG = M / 8;
    constexpr int GPB = 256 / LPG;
    const int g = threadIdx.x / LPG;
    const int l = threadIdx.x % LPG;
    const int v = blockIdx.x * GPB + g;
    if (v >= n) return;

    const float dv = dinv[v];
    float acc[8];
    {
        uint4 u = *(const uint4*)(h + (size_t)v * M + l * 8);
        acc[0] = bflo(u.x); acc[1] = bfhi(u.x);
        acc[2] = bflo(u.y); acc[3] = bfhi(u.y);
        acc[4] = bflo(u.z); acc[5] = bfhi(u.z);
        acc[6] = bflo(u.w); acc[7] = bfhi(u.w);
    }

    int j   = row_ptr[v];
    int end = row_ptr[v + 1];
    for (; j + 3 < end; j += 4) {
        int s0 = __builtin_nontemporal_load(csr_src + j);
        int s1 = __builtin_nontemporal_load(csr_src + j + 1);
        int s2 = __builtin_nontemporal_load(csr_src + j + 2);
        int s3 = __builtin_nontemporal_load(csr_src + j + 3);
        uint4 u0 = *(const uint4*)(h + (size_t)s0 * M + l * 8);
        uint4 u1 = *(const uint4*)(h + (size_t)s1 * M + l * 8);
        uint4 u2 = *(const uint4*)(h + (size_t)s2 * M + l * 8);
        uint4 u3 = *(const uint4*)(h + (size_t)s3 * M + l * 8);
        acc[0] += (bflo(u0.x) + bflo(u1.x)) + (bflo(u2.x) + bflo(u3.x));
        acc[1] += (bfhi(u0.x) + bfhi(u1.x)) + (bfhi(u2.x) + bfhi(u3.x));
        acc[2] += (bflo(u0.y) + bflo(u1.y)) + (bflo(u2.y) + bflo(u3.y));
        acc[3] += (bfhi(u0.y) + bfhi(u1.y)) + (bfhi(u2.y) + bfhi(u3.y));
        acc[4] += (bflo(u0.z) + bflo(u1.z)) + (bflo(u2.z) + bflo(u3.z));
        acc[5] += (bfhi(u0.z) + bfhi(u1.z)) + (bfhi(u2.z) + bfhi(u3.z));
        acc[6] += (bflo(u0.w) + bflo(u1.w)) + (bflo(u2.w) + bflo(u3.w));
        acc[7] += (bfhi(u0.w) + bfhi(u1.w)) + (bfhi(u2.w) + bfhi(u3.w));
    }
    for (; j < end; j++) {
        int s0 = __builtin_nontemporal_load(csr_src + j);
        uint4 u0 = *(const uint4*)(h + (size_t)s0 * M + l * 8);
        acc[0] += bflo(u0.x); acc[1] += bfhi(u0.x);
        acc[2] += bflo(u0.y); acc[3] += bfhi(u0.y);
        acc[4] += bflo(u0.z); acc[5] += bfhi(u0.z);
        acc[6] += bflo(u0.w); acc[7] += bfhi(u0.w);
    }

#pragma unroll
    for (int i = 0; i < 8; i++) {
        acc[i] = acc[i] * dv + bias[l * 8 + i];
        if (RELU) acc[i] = fmaxf(acc[i], 0.0f);
    }

    if constexpr (OBF16) {
        uivec4 p;
#pragma unroll
        for (int c = 0; c < 4; c++)
            p[c] = (uint32)f2bf(acc[2 * c]) | ((uint32)f2bf(acc[2 * c + 1]) << 16);
        __builtin_nontemporal_store(p,
            (uivec4*)((unsigned short*)outp + (size_t)v * M + l * 8));
    } else {
        float* op = (float*)outp + (size_t)v * M + l * 8;
        fvec4 a0 = {acc[0], acc[1], acc[2], acc[3]};
        fvec4 a1 = {acc[4], acc[5], acc[6], acc[7]};
        __builtin_nontemporal_store(a0, (fvec4*)op);
        __builtin_nontemporal_store(a1, (fvec4*)(op + 4));
    }
}

extern "C" void kernel_launch(void* const* d_in, const int* in_sizes, int n_in,
                              void* d_out, int out_size, void* d_ws, size_t ws_size,
                              hipStream_t stream) {
    const float* x  = (const float*)d_in[0];
    const float* W1 = (const float*)d_in[1];
    const float* b1 = (const float*)d_in[2];
    const float* W2 = (const float*)d_in[3];
    const float* b2 = (const float*)d_in[4];
    const int*   ei = (const int*)d_in[5];
    const int* src = ei;            // edge_index[0]
    const int* dst = ei + NEDGES;   // edge_index[1]
    float* out = (float*)d_out;

    // workspace layout (16B-aligned chunks):
    char* ws = (char*)d_ws;
    float*  dinv    = (float*)ws;   ws += (size_t)NNODES * 4;
    int*    row_ptr = (int*)ws;     ws += (size_t)(NNODES + 4) * 4;
    int*    bcnt    = (int*)ws;     ws += 256 * 4;
    int*    boff    = (int*)ws;     ws += 260 * 4;
    unsigned short* wt1 = (unsigned short*)ws;  ws += (size_t)IND * HIDD * 2;
    unsigned short* wt2 = (unsigned short*)ws;  ws += (size_t)HIDD * OUTD * 2;
    int*    csr_src = (int*)ws;     ws += (size_t)NEDGES * 4;
    uint32* staging = (uint32*)ws;  ws += (size_t)NBUCK * SLACK * 4;   // 7.2 MB
    unsigned short* hr  = (unsigned short*)ws;  ws += (size_t)NNODES * HIDD * 2;  // bf16 relu output
    unsigned short* hbf = (unsigned short*)ws;                                     // bf16 table

    // ---- CSR build (2 kernels; weight transpose fused into k_bin tail blocks) ----
    hipMemsetAsync(bcnt, 0, 256 * 4, stream);
    k_bin<<<BINB + WTB, 256, 0, stream>>>(src, dst, bcnt, staging, NEDGES, W1, W2, wt1, wt2);
    k_fill3<<<NBUCK, 256, 0, stream>>>(staging, bcnt, row_ptr, csr_src, dinv, NNODES);

    // ---- layer 1: hbf(bf16) = (x @ W1)*dinv ; hr(bf16) = relu(gather*dv + b1) ----
    gemm_mfma<IND, HIDD, false><<<(NNODES + 63) / 64, 256, 0, stream>>>(
        x, wt1, dinv, hbf, NNODES);
    gather_k<HIDD, true, true><<<(NNODES * (HIDD / 8) + 255) / 256, 256, 0, stream>>>(
        hbf, row_ptr, csr_src, dinv, b1, hr, NNODES);

    // ---- layer 2: hbf(bf16) = (hr @ W2)*dinv ; out(f32) = gather*dv + b2 ----
    gemm_mfma<HIDD, OUTD, true><<<(NNODES + 63) / 64, 256, 0, stream>>>(
        hr, wt2, dinv, hbf, NNODES);
    gather_k<OUTD, false, false><<<(NNODES * (OUTD / 8) + 255) / 256, 256, 0, stream>>>(
        hbf, row_ptr, csr_src, dinv, b2, out, NNODES);
}

// Round 4
// 316.845 us; speedup vs baseline: 1.2340x; 1.0311x over previous
//
#include <hip/hip_runtime.h>

#define NNODES 100000
#define NEDGES 1600000
#define IND 128
#define HIDD 128
#define OUTD 64

// bucketed CSR build
#define BSHIFT 9
#define BSIZE  512
#define NBUCK  ((NNODES + BSIZE - 1) / BSIZE)        // 196
#define SLACK  9216                                  // per-bucket staging stride (mean 8192 + 11 sigma)
#define BIN_EPB  8192
#define SEG_CAP  10240
#define BINB   ((NEDGES + BIN_EPB - 1) / BIN_EPB)    // 196
#define WTB    ((IND * HIDD + HIDD * OUTD + 255) / 256)  // 96

typedef unsigned int  uint32;
typedef __attribute__((ext_vector_type(8))) short short8;
typedef __attribute__((ext_vector_type(4))) float floatx4;
typedef __attribute__((ext_vector_type(4))) unsigned int uivec4;
typedef __attribute__((ext_vector_type(4))) float fvec4;

// ---------- bf16 helpers ----------
__device__ __forceinline__ unsigned short f2bf(float f) {
    union { float f; uint32 u; } x; x.f = f;
    uint32 u = x.u;
    return (unsigned short)((u + 0x7fffu + ((u >> 16) & 1u)) >> 16);   // RNE
}
__device__ __forceinline__ float bflo(uint32 u) {
    union { uint32 i; float f; } x; x.i = u << 16; return x.f;
}
__device__ __forceinline__ float bfhi(uint32 u) {
    union { uint32 i; float f; } x; x.i = u & 0xffff0000u; return x.f;
}

// ---------- phase A: bin (src,dst) into bucket staging; tail blocks do weight transposes ----------
__global__ void k_bin(const int* __restrict__ src, const int* __restrict__ dst,
                      int* __restrict__ bcnt, uint32* __restrict__ staging, int e,
                      const float* __restrict__ W1, const float* __restrict__ W2,
                      unsigned short* __restrict__ wt1, unsigned short* __restrict__ wt2) {
    const int tid = threadIdx.x;
    if (blockIdx.x >= BINB) {
        // weight transpose blocks
        int idx = (blockIdx.x - BINB) * 256 + tid;
        if (idx < IND * HIDD) {
            int k = idx / HIDD, m = idx - k * HIDD;
            wt1[m * IND + k] = f2bf(W1[idx]);
        } else {
            int j = idx - IND * HIDD;
            if (j < HIDD * OUTD) {
                int k = j / OUTD, m = j - k * OUTD;
                wt2[m * HIDD + k] = f2bf(W2[j]);
            }
        }
        return;
    }

    __shared__ int lh[NBUCK];
    __shared__ int lcur[NBUCK];
    for (int i = tid; i < NBUCK; i += 256) lh[i] = 0;
    __syncthreads();

    int start = blockIdx.x * BIN_EPB;
    int end = min(start + BIN_EPB, e);

    for (int i = start + tid; i < end; i += 256)
        atomicAdd(&lh[dst[i] >> BSHIFT], 1);
    __syncthreads();

    for (int i = tid; i < NBUCK; i += 256)
        lcur[i] = lh[i] ? atomicAdd(&bcnt[i], lh[i]) : 0;
    __syncthreads();

    for (int i = start + tid; i < end; i += 256) {
        int d = dst[i], s = src[i];
        int b = d >> BSHIFT;
        int pos = atomicAdd(&lcur[b], 1);
        if (pos < SLACK)
            staging[b * SLACK + pos] = ((uint32)(d & (BSIZE - 1)) << 17) | (uint32)s;
    }
}

// ---------- phase C (fused): self-scan of bcnt + per-bucket counts + dinv + row_ptr + counting-sort csr ----------
__global__ void k_fill3(const uint32* __restrict__ staging, const int* __restrict__ bcnt,
                        int* __restrict__ row_ptr, int* __restrict__ csr_src,
                        float* __restrict__ dinv, int n) {
    __shared__ int nc[BSIZE];
    __shared__ int lcur[BSIZE];
    __shared__ int sbuf[256];
    __shared__ int boffl[NBUCK + 1];
    __shared__ int seg[SEG_CAP];    // 40 KB
    const int b = blockIdx.x;
    const int base = b << BSHIFT;
    const int tid = threadIdx.x;
    const int nn = min(BSIZE, n - base);

    for (int i = tid; i < BSIZE; i += 256) nc[i] = 0;

    // self-scan of bucket counts -> exclusive offsets (replaces k_bscan kernel)
    int vb = (tid < NBUCK) ? bcnt[tid] : 0;
    sbuf[tid] = vb;
    __syncthreads();
    for (int off = 1; off < 256; off <<= 1) {
        int t = (tid >= off) ? sbuf[tid - off] : 0;
        __syncthreads();
        sbuf[tid] += t;
        __syncthreads();
    }
    if (tid < NBUCK) boffl[tid] = sbuf[tid] - vb;
    if (tid == 255) boffl[NBUCK] = sbuf[255];
    __syncthreads();

    const uint32* st = staging + (size_t)b * SLACK;
    const int cnt = bcnt[b];
    for (int i = tid; i < cnt; i += 256)
        atomicAdd(&nc[st[i] >> 17], 1);
    __syncthreads();

    int a0 = nc[2 * tid], a1 = nc[2 * tid + 1];
    sbuf[tid] = a0 + a1;
    __syncthreads();
    for (int off = 1; off < 256; off <<= 1) {
        int t = (tid >= off) ? sbuf[tid - off] : 0;
        __syncthreads();
        sbuf[tid] += t;
        __syncthreads();
    }
    int ex = sbuf[tid] - (a0 + a1);
    const int r0 = boffl[b];
    if (2 * tid < nn) {
        row_ptr[base + 2 * tid] = r0 + ex;
        dinv[base + 2 * tid] = rsqrtf((float)(a0 + 1));
    }
    if (2 * tid + 1 < nn) {
        row_ptr[base + 2 * tid + 1] = r0 + ex + a0;
        dinv[base + 2 * tid + 1] = rsqrtf((float)(a1 + 1));
    }
    lcur[2 * tid] = ex;
    lcur[2 * tid + 1] = ex + a0;
    if (b == (int)gridDim.x - 1 && tid == 255) row_ptr[n] = boffl[NBUCK];
    __syncthreads();

    for (int i = tid; i < cnt; i += 256) {
        uint32 p = st[i];
        int dl = (int)(p >> 17);
        int s  = (int)(p & 0x1FFFFu);
        int pos = atomicAdd(&lcur[dl], 1);
        if (pos < SEG_CAP) seg[pos] = s;
        else               csr_src[r0 + pos] = s;
    }
    __syncthreads();
    int lim = min(cnt, SEG_CAP);
    for (int i = tid; i < lim; i += 256) csr_src[r0 + i] = seg[i];
}

// ---------- MFMA bf16 GEMM: 128-row tiles, 512 threads (8 waves) ----------
// C[n x M](bf16, premult dinv) = A[n x K] @ W.  W staged once per 128 rows.
template<int K, int M, bool ABF16>
__launch_bounds__(512)
__global__ void gemm_mfma(const void* __restrict__ Ap, const unsigned short* __restrict__ WT,
                          const float* __restrict__ dinv, unsigned short* __restrict__ C, int n) {
    constexpr int KP = K + 8;
    constexpr int NT = M / 16;
    __shared__ unsigned short Asl[128 * KP];
    __shared__ unsigned short Wsl[M * KP];

    const int tid = threadIdx.x;
    const int row0 = blockIdx.x * 128;

    {
        constexpr int SEG = (K * 2) / 16;
        const uint4* srcp = (const uint4*)WT;
        for (int idx = tid; idx < M * SEG; idx += 512) {
            int r = idx / SEG, s = idx - r * SEG;
            *(uint4*)(Wsl + r * KP + s * 8) = srcp[idx];
        }
    }
    if constexpr (ABF16) {
        constexpr int U4R = K / 8;
        const unsigned short* Ab = (const unsigned short*)Ap;
        for (int idx = tid; idx < 128 * U4R; idx += 512) {
            int r = idx / U4R, s = idx - r * U4R;
            int grow = row0 + r; if (grow >= n) grow = n - 1;
            *(uint4*)(Asl + r * KP + s * 8) = *(const uint4*)(Ab + (size_t)grow * K + s * 8);
        }
    } else {
        constexpr int F4R = K / 4;
        const float* Af = (const float*)Ap;
        for (int idx = tid; idx < 128 * F4R; idx += 512) {
            int r = idx / F4R, s = idx - r * F4R;
            int grow = row0 + r; if (grow >= n) grow = n - 1;
            float4 v = *(const float4*)(Af + (size_t)grow * K + s * 4);
            uint32 p0 = (uint32)f2bf(v.x) | ((uint32)f2bf(v.y) << 16);
            uint32 p1 = (uint32)f2bf(v.z) | ((uint32)f2bf(v.w) << 16);
            *(uint2*)(Asl + r * KP + s * 4) = make_uint2(p0, p1);
        }
    }
    __syncthreads();

    const int lane = tid & 63;
    const int wave = tid >> 6;          // 0..7 -> rows wave*16 .. wave*16+15
    const int mm = lane & 15;
    const int qq = lane >> 4;

    floatx4 acc[NT];
#pragma unroll
    for (int t = 0; t < NT; t++) acc[t] = (floatx4){0.f, 0.f, 0.f, 0.f};

#pragma unroll
    for (int kc = 0; kc < K / 32; kc++) {
        short8 a = *(const short8*)(Asl + (wave * 16 + mm) * KP + kc * 32 + qq * 8);
#pragma unroll
        for (int t = 0; t < NT; t++) {
            short8 b = *(const short8*)(Wsl + (t * 16 + mm) * KP + kc * 32 + qq * 8);
            acc[t] = __builtin_amdgcn_mfma_f32_16x16x32_bf16(a, b, acc[t], 0, 0, 0);
        }
    }

#pragma unroll
    for (int r = 0; r < 4; r++) {
        int grow = row0 + wave * 16 + qq * 4 + r;
        if (grow < n) {
            float dv = dinv[grow];
#pragma unroll
            for (int t = 0; t < NT; t++)
                C[(size_t)grow * M + t * 16 + mm] = f2bf(acc[t][r] * dv);
        }
    }
}

// ---------- gather-aggregate over premultiplied bf16 table (node-major rows) ----------
template<int M, bool RELU, bool OBF16>
__launch_bounds__(256)
__global__ void gather_k(const unsigned short* __restrict__ h,
                         const int* __restrict__ row_ptr,
                         const int* __restrict__ csr_src,
                         const float* __restrict__ dinv,
                         const float* __restrict__ bias,
                         void* __restrict__ outp, int n) {
    constexpr int LPG = M / 8;
    constexpr int GPB = 256 / LPG;
    const int g = threadIdx.x / LPG;
    const int l = threadIdx.x % LPG;
    const int v = blockIdx.x * GPB + g;
    if (v >= n) return;

    const float dv = dinv[v];
    float acc[8];
    {
        uint4 u = *(const uint4*)(h + (size_t)v * M + l * 8);
        acc[0] = bflo(u.x); acc[1] = bfhi(u.x);
        acc[2] = bflo(u.y); acc[3] = bfhi(u.y);
        acc[4] = bflo(u.z); acc[5] = bfhi(u.z);
        acc[6] = bflo(u.w); acc[7] = bfhi(u.w);
    }

    int j   = row_ptr[v];
    int end = row_ptr[v + 1];
    for (; j + 3 < end; j += 4) {
        int s0 = csr_src[j];
        int s1 = csr_src[j + 1];
        int s2 = csr_src[j + 2];
        int s3 = csr_src[j + 3];
        uint4 u0 = *(const uint4*)(h + (size_t)s0 * M + l * 8);
        uint4 u1 = *(const uint4*)(h + (size_t)s1 * M + l * 8);
        uint4 u2 = *(const uint4*)(h + (size_t)s2 * M + l * 8);
        uint4 u3 = *(const uint4*)(h + (size_t)s3 * M + l * 8);
        acc[0] += (bflo(u0.x) + bflo(u1.x)) + (bflo(u2.x) + bflo(u3.x));
        acc[1] += (bfhi(u0.x) + bfhi(u1.x)) + (bfhi(u2.x) + bfhi(u3.x));
        acc[2] += (bflo(u0.y) + bflo(u1.y)) + (bflo(u2.y) + bflo(u3.y));
        acc[3] += (bfhi(u0.y) + bfhi(u1.y)) + (bfhi(u2.y) + bfhi(u3.y));
        acc[4] += (bflo(u0.z) + bflo(u1.z)) + (bflo(u2.z) + bflo(u3.z));
        acc[5] += (bfhi(u0.z) + bfhi(u1.z)) + (bfhi(u2.z) + bfhi(u3.z));
        acc[6] += (bflo(u0.w) + bflo(u1.w)) + (bflo(u2.w) + bflo(u3.w));
        acc[7] += (bfhi(u0.w) + bfhi(u1.w)) + (bfhi(u2.w) + bfhi(u3.w));
    }
    for (; j < end; j++) {
        int s0 = csr_src[j];
        uint4 u0 = *(const uint4*)(h + (size_t)s0 * M + l * 8);
        acc[0] += bflo(u0.x); acc[1] += bfhi(u0.x);
        acc[2] += bflo(u0.y); acc[3] += bfhi(u0.y);
        acc[4] += bflo(u0.z); acc[5] += bfhi(u0.z);
        acc[6] += bflo(u0.w); acc[7] += bfhi(u0.w);
    }

#pragma unroll
    for (int i = 0; i < 8; i++) {
        acc[i] = acc[i] * dv + bias[l * 8 + i];
        if (RELU) acc[i] = fmaxf(acc[i], 0.0f);
    }

    if constexpr (OBF16) {
        uivec4 p;
#pragma unroll
        for (int c = 0; c < 4; c++)
            p[c] = (uint32)f2bf(acc[2 * c]) | ((uint32)f2bf(acc[2 * c + 1]) << 16);
        __builtin_nontemporal_store(p,
            (uivec4*)((unsigned short*)outp + (size_t)v * M + l * 8));
    } else {
        float* op = (float*)outp + (size_t)v * M + l * 8;
        fvec4 a0 = {acc[0], acc[1], acc[2], acc[3]};
        fvec4 a1 = {acc[4], acc[5], acc[6], acc[7]};
        __builtin_nontemporal_store(a0, (fvec4*)op);
        __builtin_nontemporal_store(a1, (fvec4*)(op + 4));
    }
}

extern "C" void kernel_launch(void* const* d_in, const int* in_sizes, int n_in,
                              void* d_out, int out_size, void* d_ws, size_t ws_size,
                              hipStream_t stream) {
    const float* x  = (const float*)d_in[0];
    const float* W1 = (const float*)d_in[1];
    const float* b1 = (const float*)d_in[2];
    const float* W2 = (const float*)d_in[3];
    const float* b2 = (const float*)d_in[4];
    const int*   ei = (const int*)d_in[5];
    const int* src = ei;            // edge_index[0]
    const int* dst = ei + NEDGES;   // edge_index[1]
    float* out = (float*)d_out;

    // workspace layout (16B-aligned chunks):
    char* ws = (char*)d_ws;
    float*  dinv    = (float*)ws;   ws += (size_t)NNODES * 4;
    int*    row_ptr = (int*)ws;     ws += (size_t)(NNODES + 4) * 4;
    int*    bcnt    = (int*)ws;     ws += 256 * 4;
    int*    boff    = (int*)ws;     ws += 260 * 4;
    unsigned short* wt1 = (unsigned short*)ws;  ws += (size_t)IND * HIDD * 2;
    unsigned short* wt2 = (unsigned short*)ws;  ws += (size_t)HIDD * OUTD * 2;
    int*    csr_src = (int*)ws;     ws += (size_t)NEDGES * 4;
    uint32* staging = (uint32*)ws;  ws += (size_t)NBUCK * SLACK * 4;   // 7.2 MB
    unsigned short* hr  = (unsigned short*)ws;  ws += (size_t)NNODES * HIDD * 2;  // bf16 relu output
    unsigned short* hbf = (unsigned short*)ws;                                     // bf16 table

    // ---- CSR build (2 kernels; weight transpose fused into k_bin tail blocks) ----
    hipMemsetAsync(bcnt, 0, 256 * 4, stream);
    k_bin<<<BINB + WTB, 256, 0, stream>>>(src, dst, bcnt, staging, NEDGES, W1, W2, wt1, wt2);
    k_fill3<<<NBUCK, 256, 0, stream>>>(staging, bcnt, row_ptr, csr_src, dinv, NNODES);

    // ---- layer 1: hbf(bf16) = (x @ W1)*dinv ; hr(bf16) = relu(gather*dv + b1) ----
    gemm_mfma<IND, HIDD, false><<<(NNODES + 127) / 128, 512, 0, stream>>>(
        x, wt1, dinv, hbf, NNODES);
    gather_k<HIDD, true, true><<<(NNODES * (HIDD / 8) + 255) / 256, 256, 0, stream>>>(
        hbf, row_ptr, csr_src, dinv, b1, hr, NNODES);

    // ---- layer 2: hbf(bf16) = (hr @ W2)*dinv ; out(f32) = gather*dv + b2 ----
    gemm_mfma<HIDD, OUTD, true><<<(NNODES + 127) / 128, 512, 0, stream>>>(
        hr, wt2, dinv, hbf, NNODES);
    gather_k<OUTD, false, false><<<(NNODES * (OUTD / 8) + 255) / 256, 256, 0, stream>>>(
        hbf, row_ptr, csr_src, dinv, b2, out, NNODES);
}

// Round 5
// 306.860 us; speedup vs baseline: 1.2742x; 1.0325x over previous
//
#include <hip/hip_runtime.h>

#define NNODES 100000
#define NEDGES 1600000
#define IND 128
#define HIDD 128
#define OUTD 64

// bucketed CSR build
#define BSHIFT 9
#define BSIZE  512
#define NBUCK  ((NNODES + BSIZE - 1) / BSIZE)        // 196
#define SLACK  9216                                  // per-bucket staging stride (mean 8192 + 11 sigma)
#define BIN_EPB  8192
#define SEG_CAP  10240
#define BINB   ((NEDGES + BIN_EPB - 1) / BIN_EPB)    // 196
#define WTB    ((IND * HIDD + HIDD * OUTD + 255) / 256)  // 96

typedef unsigned int  uint32;
typedef __attribute__((ext_vector_type(8))) short short8;
typedef __attribute__((ext_vector_type(4))) float floatx4;
typedef __attribute__((ext_vector_type(4))) unsigned int uivec4;
typedef __attribute__((ext_vector_type(4))) float fvec4;

// ---------- bf16 helpers ----------
__device__ __forceinline__ unsigned short f2bf(float f) {
    union { float f; uint32 u; } x; x.f = f;
    uint32 u = x.u;
    return (unsigned short)((u + 0x7fffu + ((u >> 16) & 1u)) >> 16);   // RNE
}
__device__ __forceinline__ float bflo(uint32 u) {
    union { uint32 i; float f; } x; x.i = u << 16; return x.f;
}
__device__ __forceinline__ float bfhi(uint32 u) {
    union { uint32 i; float f; } x; x.i = u & 0xffff0000u; return x.f;
}

// ---------- phase A: bin (src,dst) into bucket staging; tail blocks do weight transposes ----------
__global__ void k_bin(const int* __restrict__ src, const int* __restrict__ dst,
                      int* __restrict__ bcnt, uint32* __restrict__ staging, int e,
                      const float* __restrict__ W1, const float* __restrict__ W2,
                      unsigned short* __restrict__ wt1, unsigned short* __restrict__ wt2) {
    const int tid = threadIdx.x;
    if (blockIdx.x >= BINB) {
        // weight transpose blocks
        int idx = (blockIdx.x - BINB) * 256 + tid;
        if (idx < IND * HIDD) {
            int k = idx / HIDD, m = idx - k * HIDD;
            wt1[m * IND + k] = f2bf(W1[idx]);
        } else {
            int j = idx - IND * HIDD;
            if (j < HIDD * OUTD) {
                int k = j / OUTD, m = j - k * OUTD;
                wt2[m * HIDD + k] = f2bf(W2[j]);
            }
        }
        return;
    }

    __shared__ int lh[NBUCK];
    __shared__ int lcur[NBUCK];
    for (int i = tid; i < NBUCK; i += 256) lh[i] = 0;
    __syncthreads();

    int start = blockIdx.x * BIN_EPB;
    int end = min(start + BIN_EPB, e);

    for (int i = start + tid; i < end; i += 256)
        atomicAdd(&lh[dst[i] >> BSHIFT], 1);
    __syncthreads();

    for (int i = tid; i < NBUCK; i += 256)
        lcur[i] = lh[i] ? atomicAdd(&bcnt[i], lh[i]) : 0;
    __syncthreads();

    for (int i = start + tid; i < end; i += 256) {
        int d = dst[i], s = src[i];
        int b = d >> BSHIFT;
        int pos = atomicAdd(&lcur[b], 1);
        if (pos < SLACK)
            staging[b * SLACK + pos] = ((uint32)(d & (BSIZE - 1)) << 17) | (uint32)s;
    }
}

// ---------- phase C (fused): self-scan of bcnt + per-bucket counts + dinv + row_ptr + counting-sort csr ----------
__global__ void k_fill3(const uint32* __restrict__ staging, const int* __restrict__ bcnt,
                        int* __restrict__ row_ptr, int* __restrict__ csr_src,
                        float* __restrict__ dinv, int n) {
    __shared__ int nc[BSIZE];
    __shared__ int lcur[BSIZE];
    __shared__ int sbuf[256];
    __shared__ int boffl[NBUCK + 1];
    __shared__ int seg[SEG_CAP];    // 40 KB
    const int b = blockIdx.x;
    const int base = b << BSHIFT;
    const int tid = threadIdx.x;
    const int nn = min(BSIZE, n - base);

    for (int i = tid; i < BSIZE; i += 256) nc[i] = 0;

    // self-scan of bucket counts -> exclusive offsets
    int vb = (tid < NBUCK) ? bcnt[tid] : 0;
    sbuf[tid] = vb;
    __syncthreads();
    for (int off = 1; off < 256; off <<= 1) {
        int t = (tid >= off) ? sbuf[tid - off] : 0;
        __syncthreads();
        sbuf[tid] += t;
        __syncthreads();
    }
    if (tid < NBUCK) boffl[tid] = sbuf[tid] - vb;
    if (tid == 255) boffl[NBUCK] = sbuf[255];
    __syncthreads();

    const uint32* st = staging + (size_t)b * SLACK;
    const int cnt = bcnt[b];
    for (int i = tid; i < cnt; i += 256)
        atomicAdd(&nc[st[i] >> 17], 1);
    __syncthreads();

    int a0 = nc[2 * tid], a1 = nc[2 * tid + 1];
    sbuf[tid] = a0 + a1;
    __syncthreads();
    for (int off = 1; off < 256; off <<= 1) {
        int t = (tid >= off) ? sbuf[tid - off] : 0;
        __syncthreads();
        sbuf[tid] += t;
        __syncthreads();
    }
    int ex = sbuf[tid] - (a0 + a1);
    const int r0 = boffl[b];
    if (2 * tid < nn) {
        row_ptr[base + 2 * tid] = r0 + ex;
        dinv[base + 2 * tid] = rsqrtf((float)(a0 + 1));
    }
    if (2 * tid + 1 < nn) {
        row_ptr[base + 2 * tid + 1] = r0 + ex + a0;
        dinv[base + 2 * tid + 1] = rsqrtf((float)(a1 + 1));
    }
    lcur[2 * tid] = ex;
    lcur[2 * tid + 1] = ex + a0;
    if (b == (int)gridDim.x - 1 && tid == 255) row_ptr[n] = boffl[NBUCK];
    __syncthreads();

    for (int i = tid; i < cnt; i += 256) {
        uint32 p = st[i];
        int dl = (int)(p >> 17);
        int s  = (int)(p & 0x1FFFFu);
        int pos = atomicAdd(&lcur[dl], 1);
        if (pos < SEG_CAP) seg[pos] = s;
        else               csr_src[r0 + pos] = s;
    }
    __syncthreads();
    int lim = min(cnt, SEG_CAP);
    for (int i = tid; i < lim; i += 256) csr_src[r0 + i] = seg[i];
}

// ---------- MFMA bf16 GEMM: 128-row tiles, 512 threads (8 waves) ----------
// C[n x M](bf16, premult dinv) = A[n x K] @ W.  W staged once per 128 rows.
template<int K, int M, bool ABF16>
__launch_bounds__(512)
__global__ void gemm_mfma(const void* __restrict__ Ap, const unsigned short* __restrict__ WT,
                          const float* __restrict__ dinv, unsigned short* __restrict__ C, int n) {
    constexpr int KP = K + 8;
    constexpr int NT = M / 16;
    __shared__ unsigned short Asl[128 * KP];
    __shared__ unsigned short Wsl[M * KP];

    const int tid = threadIdx.x;
    const int row0 = blockIdx.x * 128;

    {
        constexpr int SEG = (K * 2) / 16;
        const uint4* srcp = (const uint4*)WT;
        for (int idx = tid; idx < M * SEG; idx += 512) {
            int r = idx / SEG, s = idx - r * SEG;
            *(uint4*)(Wsl + r * KP + s * 8) = srcp[idx];
        }
    }
    if constexpr (ABF16) {
        constexpr int U4R = K / 8;
        const unsigned short* Ab = (const unsigned short*)Ap;
        for (int idx = tid; idx < 128 * U4R; idx += 512) {
            int r = idx / U4R, s = idx - r * U4R;
            int grow = row0 + r; if (grow >= n) grow = n - 1;
            *(uint4*)(Asl + r * KP + s * 8) = *(const uint4*)(Ab + (size_t)grow * K + s * 8);
        }
    } else {
        constexpr int F4R = K / 4;
        const float* Af = (const float*)Ap;
        for (int idx = tid; idx < 128 * F4R; idx += 512) {
            int r = idx / F4R, s = idx - r * F4R;
            int grow = row0 + r; if (grow >= n) grow = n - 1;
            float4 v = *(const float4*)(Af + (size_t)grow * K + s * 4);
            uint32 p0 = (uint32)f2bf(v.x) | ((uint32)f2bf(v.y) << 16);
            uint32 p1 = (uint32)f2bf(v.z) | ((uint32)f2bf(v.w) << 16);
            *(uint2*)(Asl + r * KP + s * 4) = make_uint2(p0, p1);
        }
    }
    __syncthreads();

    const int lane = tid & 63;
    const int wave = tid >> 6;          // 0..7 -> rows wave*16 .. wave*16+15
    const int mm = lane & 15;
    const int qq = lane >> 4;

    floatx4 acc[NT];
#pragma unroll
    for (int t = 0; t < NT; t++) acc[t] = (floatx4){0.f, 0.f, 0.f, 0.f};

#pragma unroll
    for (int kc = 0; kc < K / 32; kc++) {
        short8 a = *(const short8*)(Asl + (wave * 16 + mm) * KP + kc * 32 + qq * 8);
#pragma unroll
        for (int t = 0; t < NT; t++) {
            short8 b = *(const short8*)(Wsl + (t * 16 + mm) * KP + kc * 32 + qq * 8);
            acc[t] = __builtin_amdgcn_mfma_f32_16x16x32_bf16(a, b, acc[t], 0, 0, 0);
        }
    }

#pragma unroll
    for (int r = 0; r < 4; r++) {
        int grow = row0 + wave * 16 + qq * 4 + r;
        if (grow < n) {
            float dv = dinv[grow];
#pragma unroll
            for (int t = 0; t < NT; t++)
                C[(size_t)grow * M + t * 16 + mm] = f2bf(acc[t][r] * dv);
        }
    }
}

// ---------- FUSED layer-1 gather + (hr @ W2)*dinv ----------
// Block = 256 threads = 16 nodes x 16 feature-slots. Gathers 128-feat rows from
// the premultiplied bf16 table h, applies *dv + b1, ReLU (bit-identical to the
// unfused path), stages the 16x128 hr tile in LDS, then the 4 waves compute the
// 16x64 layer-2 pre-aggregation tile via MFMA, premultiply by dinv and store C2.
// Eliminates the hr HBM round-trip (51 MB) and the gemm2 dispatch.
__launch_bounds__(256)
__global__ void gather_gemm(const unsigned short* __restrict__ h,
                            const int* __restrict__ row_ptr,
                            const int* __restrict__ csr_src,
                            const float* __restrict__ dinv,
                            const float* __restrict__ bias1,
                            const unsigned short* __restrict__ WT2,
                            unsigned short* __restrict__ C2, int n) {
    constexpr int K  = HIDD;          // 128
    constexpr int KP = K + 8;         // 136
    constexpr int M2 = OUTD;          // 64
    __shared__ unsigned short Atl[16 * KP];     // 4.3 KB hr tile
    __shared__ unsigned short Wsl[M2 * KP];     // 17 KB W2^T

    const int tid = threadIdx.x;

    // stage W2^T [64][128] -> Wsl (same layout as gemm_mfma)
    {
        constexpr int SEG = (K * 2) / 16;   // 16
        const uint4* srcp = (const uint4*)WT2;
        for (int idx = tid; idx < M2 * SEG; idx += 256) {
            int r = idx / SEG, s = idx - r * SEG;
            *(uint4*)(Wsl + r * KP + s * 8) = srcp[idx];
        }
    }

    const int g = tid >> 4;            // node within tile: 0..15
    const int l = tid & 15;            // feature slot: 0..15 (8 feats each)
    const int v0 = blockIdx.x * 16;
    const int v = v0 + g;

    uint4 pk = make_uint4(0u, 0u, 0u, 0u);
    if (v < n) {
        const float dv = dinv[v];
        float acc[8];
        {
            uint4 u = *(const uint4*)(h + (size_t)v * K + l * 8);
            acc[0] = bflo(u.x); acc[1] = bfhi(u.x);
            acc[2] = bflo(u.y); acc[3] = bfhi(u.y);
            acc[4] = bflo(u.z); acc[5] = bfhi(u.z);
            acc[6] = bflo(u.w); acc[7] = bfhi(u.w);
        }

        int j   = row_ptr[v];
        int end = row_ptr[v + 1];
        for (; j + 3 < end; j += 4) {
            int s0 = csr_src[j];
            int s1 = csr_src[j + 1];
            int s2 = csr_src[j + 2];
            int s3 = csr_src[j + 3];
            uint4 u0 = *(const uint4*)(h + (size_t)s0 * K + l * 8);
            uint4 u1 = *(const uint4*)(h + (size_t)s1 * K + l * 8);
            uint4 u2 = *(const uint4*)(h + (size_t)s2 * K + l * 8);
            uint4 u3 = *(const uint4*)(h + (size_t)s3 * K + l * 8);
            acc[0] += (bflo(u0.x) + bflo(u1.x)) + (bflo(u2.x) + bflo(u3.x));
            acc[1] += (bfhi(u0.x) + bfhi(u1.x)) + (bfhi(u2.x) + bfhi(u3.x));
            acc[2] += (bflo(u0.y) + bflo(u1.y)) + (bflo(u2.y) + bflo(u3.y));
            acc[3] += (bfhi(u0.y) + bfhi(u1.y)) + (bfhi(u2.y) + bfhi(u3.y));
            acc[4] += (bflo(u0.z) + bflo(u1.z)) + (bflo(u2.z) + bflo(u3.z));
            acc[5] += (bfhi(u0.z) + bfhi(u1.z)) + (bfhi(u2.z) + bfhi(u3.z));
            acc[6] += (bflo(u0.w) + bflo(u1.w)) + (bflo(u2.w) + bflo(u3.w));
            acc[7] += (bfhi(u0.w) + bfhi(u1.w)) + (bfhi(u2.w) + bfhi(u3.w));
        }
        for (; j < end; j++) {
            int s0 = csr_src[j];
            uint4 u0 = *(const uint4*)(h + (size_t)s0 * K + l * 8);
            acc[0] += bflo(u0.x); acc[1] += bfhi(u0.x);
            acc[2] += bflo(u0.y); acc[3] += bfhi(u0.y);
            acc[4] += bflo(u0.z); acc[5] += bfhi(u0.z);
            acc[6] += bflo(u0.w); acc[7] += bfhi(u0.w);
        }

#pragma unroll
        for (int i = 0; i < 8; i++) {
            acc[i] = fmaxf(acc[i] * dv + bias1[l * 8 + i], 0.0f);
        }
        pk.x = (uint32)f2bf(acc[0]) | ((uint32)f2bf(acc[1]) << 16);
        pk.y = (uint32)f2bf(acc[2]) | ((uint32)f2bf(acc[3]) << 16);
        pk.z = (uint32)f2bf(acc[4]) | ((uint32)f2bf(acc[5]) << 16);
        pk.w = (uint32)f2bf(acc[6]) | ((uint32)f2bf(acc[7]) << 16);
    }
    *(uint4*)(Atl + g * KP + l * 8) = pk;    // zero rows for v >= n
    __syncthreads();

    // MFMA: 16 nodes x 64 out-feats; wave wv owns column tile wv*16..wv*16+15
    const int lane = tid & 63;
    const int wv = tid >> 6;           // 0..3
    const int mm = lane & 15;
    const int qq = lane >> 4;

    floatx4 o = (floatx4){0.f, 0.f, 0.f, 0.f};
#pragma unroll
    for (int kc = 0; kc < K / 32; kc++) {
        short8 a = *(const short8*)(Atl + mm * KP + kc * 32 + qq * 8);
        short8 b = *(const short8*)(Wsl + (wv * 16 + mm) * KP + kc * 32 + qq * 8);
        o = __builtin_amdgcn_mfma_f32_16x16x32_bf16(a, b, o, 0, 0, 0);
    }

#pragma unroll
    for (int r = 0; r < 4; r++) {
        int grow = v0 + qq * 4 + r;
        if (grow < n) {
            float dv2 = dinv[grow];
            C2[(size_t)grow * M2 + wv * 16 + mm] = f2bf(o[r] * dv2);
        }
    }
}

// ---------- gather-aggregate over premultiplied bf16 table (node-major rows) ----------
template<int M, bool RELU, bool OBF16>
__launch_bounds__(256)
__global__ void gather_k(const unsigned short* __restrict__ h,
                         const int* __restrict__ row_ptr,
                         const int* __restrict__ csr_src,
                         const float* __restrict__ dinv,
                         const float* __restrict__ bias,
                         void* __restrict__ outp, int n) {
    constexpr int LPG = M / 8;
    constexpr int GPB = 256 / LPG;
    const int g = threadIdx.x / LPG;
    const int l = threadIdx.x % LPG;
    const int v = blockIdx.x * GPB + g;
    if (v >= n) return;

    const float dv = dinv[v];
    float acc[8];
    {
        uint4 u = *(const uint4*)(h + (size_t)v * M + l * 8);
        acc[0] = bflo(u.x); acc[1] = bfhi(u.x);
        acc[2] = bflo(u.y); acc[3] = bfhi(u.y);
        acc[4] = bflo(u.z); acc[5] = bfhi(u.z);
        acc[6] = bflo(u.w); acc[7] = bfhi(u.w);
    }

    int j   = row_ptr[v];
    int end = row_ptr[v + 1];
    for (; j + 3 < end; j += 4) {
        int s0 = csr_src[j];
        int s1 = csr_src[j + 1];
        int s2 = csr_src[j + 2];
        int s3 = csr_src[j + 3];
        uint4 u0 = *(const uint4*)(h + (size_t)s0 * M + l * 8);
        uint4 u1 = *(const uint4*)(h + (size_t)s1 * M + l * 8);
        uint4 u2 = *(const uint4*)(h + (size_t)s2 * M + l * 8);
        uint4 u3 = *(const uint4*)(h + (size_t)s3 * M + l * 8);
        acc[0] += (bflo(u0.x) + bflo(u1.x)) + (bflo(u2.x) + bflo(u3.x));
        acc[1] += (bfhi(u0.x) + bfhi(u1.x)) + (bfhi(u2.x) + bfhi(u3.x));
        acc[2] += (bflo(u0.y) + bflo(u1.y)) + (bflo(u2.y) + bflo(u3.y));
        acc[3] += (bfhi(u0.y) + bfhi(u1.y)) + (bfhi(u2.y) + bfhi(u3.y));
        acc[4] += (bflo(u0.z) + bflo(u1.z)) + (bflo(u2.z) + bflo(u3.z));
        acc[5] += (bfhi(u0.z) + bfhi(u1.z)) + (bfhi(u2.z) + bfhi(u3.z));
        acc[6] += (bflo(u0.w) + bflo(u1.w)) + (bflo(u2.w) + bflo(u3.w));
        acc[7] += (bfhi(u0.w) + bfhi(u1.w)) + (bfhi(u2.w) + bfhi(u3.w));
    }
    for (; j < end; j++) {
        int s0 = csr_src[j];
        uint4 u0 = *(const uint4*)(h + (size_t)s0 * M + l * 8);
        acc[0] += bflo(u0.x); acc[1] += bfhi(u0.x);
        acc[2] += bflo(u0.y); acc[3] += bfhi(u0.y);
        acc[4] += bflo(u0.z); acc[5] += bfhi(u0.z);
        acc[6] += bflo(u0.w); acc[7] += bfhi(u0.w);
    }

#pragma unroll
    for (int i = 0; i < 8; i++) {
        acc[i] = acc[i] * dv + bias[l * 8 + i];
        if (RELU) acc[i] = fmaxf(acc[i], 0.0f);
    }

    if constexpr (OBF16) {
        uivec4 p;
#pragma unroll
        for (int c = 0; c < 4; c++)
            p[c] = (uint32)f2bf(acc[2 * c]) | ((uint32)f2bf(acc[2 * c + 1]) << 16);
        __builtin_nontemporal_store(p,
            (uivec4*)((unsigned short*)outp + (size_t)v * M + l * 8));
    } else {
        float* op = (float*)outp + (size_t)v * M + l * 8;
        fvec4 a0 = {acc[0], acc[1], acc[2], acc[3]};
        fvec4 a1 = {acc[4], acc[5], acc[6], acc[7]};
        __builtin_nontemporal_store(a0, (fvec4*)op);
        __builtin_nontemporal_store(a1, (fvec4*)(op + 4));
    }
}

extern "C" void kernel_launch(void* const* d_in, const int* in_sizes, int n_in,
                              void* d_out, int out_size, void* d_ws, size_t ws_size,
                              hipStream_t stream) {
    const float* x  = (const float*)d_in[0];
    const float* W1 = (const float*)d_in[1];
    const float* b1 = (const float*)d_in[2];
    const float* W2 = (const float*)d_in[3];
    const float* b2 = (const float*)d_in[4];
    const int*   ei = (const int*)d_in[5];
    const int* src = ei;            // edge_index[0]
    const int* dst = ei + NEDGES;   // edge_index[1]
    float* out = (float*)d_out;

    // workspace layout (16B-aligned chunks):
    char* ws = (char*)d_ws;
    float*  dinv    = (float*)ws;   ws += (size_t)NNODES * 4;
    int*    row_ptr = (int*)ws;     ws += (size_t)(NNODES + 4) * 4;
    int*    bcnt    = (int*)ws;     ws += 256 * 4;
    int*    boff    = (int*)ws;     ws += 260 * 4;
    unsigned short* wt1 = (unsigned short*)ws;  ws += (size_t)IND * HIDD * 2;
    unsigned short* wt2 = (unsigned short*)ws;  ws += (size_t)HIDD * OUTD * 2;
    int*    csr_src = (int*)ws;     ws += (size_t)NEDGES * 4;
    uint32* staging = (uint32*)ws;  ws += (size_t)NBUCK * SLACK * 4;   // 7.2 MB
    unsigned short* hbf1 = (unsigned short*)ws; ws += (size_t)NNODES * HIDD * 2;  // layer-1 bf16 table
    unsigned short* hbf2 = (unsigned short*)ws;                                    // layer-2 bf16 table

    // ---- CSR build (2 kernels; weight transpose fused into k_bin tail blocks) ----
    hipMemsetAsync(bcnt, 0, 256 * 4, stream);
    k_bin<<<BINB + WTB, 256, 0, stream>>>(src, dst, bcnt, staging, NEDGES, W1, W2, wt1, wt2);
    k_fill3<<<NBUCK, 256, 0, stream>>>(staging, bcnt, row_ptr, csr_src, dinv, NNODES);

    // ---- layer 1 GEMM: hbf1(bf16) = (x @ W1)*dinv ----
    gemm_mfma<IND, HIDD, false><<<(NNODES + 127) / 128, 512, 0, stream>>>(
        x, wt1, dinv, hbf1, NNODES);

    // ---- fused: gather1 (+b1, ReLU) -> @W2 -> *dinv -> hbf2(bf16) ----
    gather_gemm<<<(NNODES + 15) / 16, 256, 0, stream>>>(
        hbf1, row_ptr, csr_src, dinv, b1, wt2, hbf2, NNODES);

    // ---- layer 2 gather: out(f32) = gather(hbf2)*dv + b2 ----
    gather_k<OUTD, false, false><<<(NNODES * (OUTD / 8) + 255) / 256, 256, 0, stream>>>(
        hbf2, row_ptr, csr_src, dinv, b2, out, NNODES);
}